// Round 8
// baseline (1067.548 us; speedup 1.0000x reference)
//
#include <hip/hip_runtime.h>
#include <hip/hip_bf16.h>
#include <math.h>

#define NPOS 81920   // 512*8*4*5
#define CDIM 256
#define SIGMA 1e-4f
#define LEAK 0.2f

typedef __hip_bfloat16 bf16;
typedef __bf16 bf16x8 __attribute__((ext_vector_type(8)));
typedef float f32x4 __attribute__((ext_vector_type(4)));

__device__ __forceinline__ float bf2f(unsigned short u) {
    return __uint_as_float(((unsigned)u) << 16);
}
__device__ __forceinline__ unsigned short f2bfu(float f) {
    bf16 h = __float2bfloat16(f);
    return *reinterpret_cast<unsigned short*>(&h);
}

// ---------------- encoder: h = tanh([x+sigma*noise, rand] @ W_enc) + pos_emb ----------------
__global__ void encode_kernel(const float* __restrict__ x, const float* __restrict__ noise,
                              const float* __restrict__ rnd, const float* __restrict__ We,
                              const float* __restrict__ pe, bf16* __restrict__ H) {
    int p = blockIdx.x;
    int c = threadIdx.x;
    float a = x[p] + SIGMA * noise[p];
    float b = rnd[p];
    float v = tanhf(a * We[c] + b * We[CDIM + c]) + pe[(p % 160) * CDIM + c];
    H[(size_t)p * CDIM + c] = __float2bfloat16(v);
}

// ---------------- bsum[l][c] = bo[l,0,c]+bo[l,1,c]+bo[l,2,c] ----------------
__global__ void bias3_kernel(const float* __restrict__ bo, float* __restrict__ bsum) {
    int l = blockIdx.x, c = threadIdx.x;
    bsum[l * CDIM + c] = bo[l * 768 + c] + bo[l * 768 + 256 + c] + bo[l * 768 + 512 + c];
}

// ---------------- weight packs ----------------
// WqkvT layout [l][a*768+n][k] (== [l][2304][256] B^T): n<256 -> Wq, else Wkv (k then v)
__global__ void pack_qkv_kernel(const float* __restrict__ Wq, const float* __restrict__ Wkv,
                                bf16* __restrict__ out) {
    int mat = blockIdx.x / 768;
    int n = blockIdx.x % 768;
    int k = threadIdx.x;
    float v = (n < 256) ? Wq[(size_t)mat * 65536 + (size_t)k * 256 + n]
                        : Wkv[(size_t)mat * 131072 + (size_t)k * 512 + (n - 256)];
    out[(size_t)blockIdx.x * 256 + k] = __float2bfloat16(v);
}
// WoT layout [l][n][a*256+ck] (== [l][256][768] B^T over stacked K): = Wo[l][a][ck][n]
__global__ void pack_wo_kernel(const float* __restrict__ Wo, bf16* __restrict__ out) {
    int l = blockIdx.x / 256;
    int n = blockIdx.x % 256;
    int ck = threadIdx.x;
    for (int a = 0; a < 3; a++)
        out[(size_t)(l * 256 + n) * 768 + a * 256 + ck] =
            __float2bfloat16(Wo[(((size_t)(l * 3 + a)) * 256 + ck) * 256 + n]);
}

// ---------------- B-register MFMA GEMM (K=256): C[M x N] = A[M x 256] @ B^T[N x 256]^T ------
// Each wave holds its entire B slice (64 cols x 256 k) in 128 VGPRs, loaded once from the
// L2-hot packed weights. K-loop ds_reads only A: 8 ds_read_b128 per 32 MFMA -> MFMA-bound.
// A staging double-buffered (2 x 16 KB LDS, XOR-swizzled). 128x128 tile, 2x2 waves of 64x64.
__global__ __launch_bounds__(256, 2) void gemm_breg(const bf16* __restrict__ A, int lda,
                                                    const bf16* __restrict__ Bt,
                                                    bf16* __restrict__ C, int ldc,
                                                    int nNblk) {
    __shared__ __bf16 Asb[2][128 * 64];
    int tid = threadIdx.x;
    int wave = tid >> 6, lane = tid & 63;
    int quad = lane >> 4, m = lane & 15;
    int nMblk = gridDim.x / nNblk;
    int mb, nb;
    if ((nMblk & 7) == 0) {
        int xcd = blockIdx.x & 7, slot = blockIdx.x >> 3;
        int g = slot / nNblk;
        nb = slot - g * nNblk;
        mb = xcd + 8 * g;
    } else {
        mb = blockIdx.x / nNblk;
        nb = blockIdx.x - mb * nNblk;
    }
    int bm = mb * 128, bn = nb * 128;
    int wr = (wave >> 1) * 64, wc = (wave & 1) * 64;

    // B fragments: bfr[kk][j] = B^T[bn+wc+j*16+m][kk*32 + quad*8 .. +8]  (one-time load)
    bf16x8 bfr[8][4];
    {
        const bf16* bp = Bt + (unsigned)(bn + wc + m) * 256 + quad * 8;
#pragma unroll
        for (int j = 0; j < 4; j++)
#pragma unroll
            for (int kk = 0; kk < 8; kk++)
                bfr[kk][j] = *(const bf16x8*)(bp + j * (16 * 256) + kk * 32);
    }

    // A staging: chunk ch = rep*256 + wave*64 + lane; row = ch>>3, col chunk ^= row&7
#define STAGE_A(buf, k0)                                                                      \
    {                                                                                         \
        _Pragma("unroll") for (int rep = 0; rep < 4; rep++) {                                 \
            int ch = rep * 256 + wave * 64 + lane;                                            \
            int row = ch >> 3, cc = ch & 7, gc = cc ^ (row & 7);                              \
            __builtin_amdgcn_global_load_lds(                                                 \
                (const __attribute__((address_space(1))) void*)(A + (size_t)(bm + row) * lda  \
                                                                + (k0) + gc * 8),             \
                (__attribute__((address_space(3))) void*)(&Asb[buf][(rep * 256 + wave * 64) * 8]), \
                16, 0, 0);                                                                    \
        }                                                                                     \
    }

    f32x4 acc[4][4] = {};
    STAGE_A(0, 0);
#pragma unroll
    for (int it = 0; it < 4; it++) {
        __syncthreads();  // drains the in-flight stage for buffer (it&1)
        if (it < 3) STAGE_A((it + 1) & 1, (it + 1) * 64);  // prefetch next while computing
        const __bf16* Ab = Asb[it & 1];
#pragma unroll
        for (int kk2 = 0; kk2 < 2; kk2++) {
            bf16x8 af[4];
#pragma unroll
            for (int i = 0; i < 4; i++) {
                int r = wr + i * 16 + m;
                af[i] = *(const bf16x8*)(Ab + r * 64 + (((kk2 * 4 + quad) ^ (r & 7)) * 8));
            }
#pragma unroll
            for (int i = 0; i < 4; i++)
#pragma unroll
                for (int j = 0; j < 4; j++)
                    acc[i][j] = __builtin_amdgcn_mfma_f32_16x16x32_bf16(
                        af[i], bfr[it * 2 + kk2][j], acc[i][j], 0, 0, 0);
        }
    }
#undef STAGE_A

    // epilogue: C/D layout col = lane&15, row = quad*4 + r
#pragma unroll
    for (int i = 0; i < 4; i++)
#pragma unroll
        for (int j = 0; j < 4; j++)
#pragma unroll
            for (int r = 0; r < 4; r++) {
                int row = bm + wr + i * 16 + quad * 4 + r;
                int col = bn + wc + j * 16 + m;
                C[(size_t)row * ldc + col] = __float2bfloat16(acc[i][j][r]);
            }
}

// ---------------- bf16 MFMA GEMM (round-7 engine, used for Wo K=768) ------------------------
// mode: 0 = store; 1 = store + bias[col] + leaky-relu.
__global__ __launch_bounds__(256) void gemm_bt(const bf16* __restrict__ A, int lda,
                                               const bf16* __restrict__ Bt, int K,
                                               bf16* __restrict__ C, int ldc,
                                               int nNblk, int mode,
                                               const float* __restrict__ bias) {
    __shared__ __bf16 Asb[128 * 64];
    __shared__ __bf16 Bsb[128 * 64];
    int tid = threadIdx.x;
    int wave = tid >> 6, lane = tid & 63;
    int quad = lane >> 4, m = lane & 15;
    int nMblk = gridDim.x / nNblk;
    int mb, nb;
    if ((nMblk & 7) == 0) {
        int xcd = blockIdx.x & 7, slot = blockIdx.x >> 3;
        int g = slot / nNblk;
        nb = slot - g * nNblk;
        mb = xcd + 8 * g;
    } else {
        mb = blockIdx.x / nNblk;
        nb = blockIdx.x - mb * nNblk;
    }
    int bm = mb * 128, bn = nb * 128;
    int wr = (wave >> 1) * 64, wc = (wave & 1) * 64;
    f32x4 acc[4][4] = {};

    for (int k0 = 0; k0 < K; k0 += 64) {
#pragma unroll
        for (int rep = 0; rep < 4; rep++) {
            int ch = rep * 256 + wave * 64 + lane;
            int row = ch >> 3, cc = ch & 7, gc = cc ^ (row & 7);
            __builtin_amdgcn_global_load_lds(
                (const __attribute__((address_space(1))) void*)(A + (size_t)(bm + row) * lda + k0 + gc * 8),
                (__attribute__((address_space(3))) void*)(Asb + (rep * 256 + wave * 64) * 8),
                16, 0, 0);
        }
#pragma unroll
        for (int rep = 0; rep < 4; rep++) {
            int ch = rep * 256 + wave * 64 + lane;
            int row = ch >> 3, cc = ch & 7, gc = cc ^ (row & 7);
            __builtin_amdgcn_global_load_lds(
                (const __attribute__((address_space(1))) void*)(Bt + (size_t)(bn + row) * K + k0 + gc * 8),
                (__attribute__((address_space(3))) void*)(Bsb + (rep * 256 + wave * 64) * 8),
                16, 0, 0);
        }
        __syncthreads();
#pragma unroll
        for (int kk = 0; kk < 2; kk++) {
            bf16x8 af[4], bfr[4];
#pragma unroll
            for (int i = 0; i < 4; i++) {
                int r = wr + i * 16 + m, cix = kk * 4 + quad;
                af[i] = *(const bf16x8*)(Asb + r * 64 + ((cix ^ (r & 7)) * 8));
            }
#pragma unroll
            for (int j = 0; j < 4; j++) {
                int r = wc + j * 16 + m, cix = kk * 4 + quad;
                bfr[j] = *(const bf16x8*)(Bsb + r * 64 + ((cix ^ (r & 7)) * 8));
            }
#pragma unroll
            for (int i = 0; i < 4; i++)
#pragma unroll
                for (int j = 0; j < 4; j++)
                    acc[i][j] = __builtin_amdgcn_mfma_f32_16x16x32_bf16(af[i], bfr[j], acc[i][j], 0, 0, 0);
        }
        __syncthreads();
    }

#pragma unroll
    for (int i = 0; i < 4; i++) {
#pragma unroll
        for (int j = 0; j < 4; j++) {
#pragma unroll
            for (int r = 0; r < 4; r++) {
                int row = bm + wr + i * 16 + quad * 4 + r;
                int col = bn + wc + j * 16 + m;
                float v = acc[i][j][r];
                if (mode == 1) {
                    v += bias[col];
                    v = v >= 0.f ? v : LEAK * v;
                }
                C[(size_t)row * ldc + col] = __float2bfloat16(v);
            }
        }
    }
}

// ---------------- fused axial attention: all 3 axes, one dispatch ----------------
// QKV row = 2304 bf16 (= 3 x [q|k|v]); output -> O row = 768 bf16 (= [o0|o1|o2]).
template <int AXIS>
__device__ __forceinline__ void attn_axis(const bf16* __restrict__ QKV, bf16* __restrict__ O,
                                          int seq, int lane) {
    constexpr int T      = (AXIS == 0) ? 8 : (AXIS == 1) ? 4 : 5;
    constexpr int STRIDE = (AXIS == 0) ? 20 : (AXIS == 1) ? 5 : 1;
    int base;
    if (AXIS == 0)      { int b = seq / 20, r = seq % 20; base = b * 160 + r; }
    else if (AXIS == 1) { int b = seq / 40, r = seq % 40; base = b * 160 + (r / 5) * 20 + (r % 5); }
    else                { int b = seq / 32, r = seq % 32; base = b * 160 + r * 5; }

    float q[T][4], k[T][4], v[T][4];
#pragma unroll
    for (int t = 0; t < T; t++) {
        const unsigned short* rowp =
            (const unsigned short*)QKV + (size_t)(base + t * STRIDE) * 2304 + AXIS * 768 + lane * 4;
        ushort4 qu = *(const ushort4*)(rowp);
        ushort4 ku = *(const ushort4*)(rowp + 256);
        ushort4 vu = *(const ushort4*)(rowp + 512);
        q[t][0] = bf2f(qu.x); q[t][1] = bf2f(qu.y); q[t][2] = bf2f(qu.z); q[t][3] = bf2f(qu.w);
        k[t][0] = bf2f(ku.x); k[t][1] = bf2f(ku.y); k[t][2] = bf2f(ku.z); k[t][3] = bf2f(ku.w);
        v[t][0] = bf2f(vu.x); v[t][1] = bf2f(vu.y); v[t][2] = bf2f(vu.z); v[t][3] = bf2f(vu.w);
    }

#pragma unroll
    for (int t = 0; t < T; t++) {
        float sc[T];
#pragma unroll
        for (int s = 0; s < T; s++) {
            float p = q[t][0] * k[s][0] + q[t][1] * k[s][1] + q[t][2] * k[s][2] + q[t][3] * k[s][3];
            p += __shfl_xor(p, 1);
            p += __shfl_xor(p, 2);
            sc[s] = p * 0.25f;  // * DH^-0.5
        }
        float mx = sc[0];
#pragma unroll
        for (int s = 1; s < T; s++) mx = fmaxf(mx, sc[s]);
        float sum = 0.f;
#pragma unroll
        for (int s = 0; s < T; s++) { sc[s] = __expf(sc[s] - mx); sum += sc[s]; }
        float inv = 1.f / sum;
        float o0 = 0.f, o1 = 0.f, o2 = 0.f, o3 = 0.f;
#pragma unroll
        for (int s = 0; s < T; s++) {
            o0 += sc[s] * v[s][0]; o1 += sc[s] * v[s][1];
            o2 += sc[s] * v[s][2]; o3 += sc[s] * v[s][3];
        }
        ushort4 st;
        st.x = f2bfu(o0 * inv); st.y = f2bfu(o1 * inv);
        st.z = f2bfu(o2 * inv); st.w = f2bfu(o3 * inv);
        *(ushort4*)((unsigned short*)O + (size_t)(base + t * STRIDE) * 768 + AXIS * 256 + lane * 4) = st;
    }
}

__global__ __launch_bounds__(256) void attn_all(const bf16* __restrict__ QKV,
                                                bf16* __restrict__ O, int n0, int n1) {
    int wave = threadIdx.x >> 6, lane = threadIdx.x & 63;
    int blk = blockIdx.x;
    if (blk < n0)            attn_axis<0>(QKV, O, blk * 4 + wave, lane);
    else if (blk < n0 + n1)  attn_axis<1>(QKV, O, (blk - n0) * 4 + wave, lane);
    else                     attn_axis<2>(QKV, O, (blk - n0 - n1) * 4 + wave, lane);
}

// ---------------- decoder: out = sigmoid(H @ Wd + bd) ----------------
__global__ void decode_kernel(const bf16* __restrict__ H, const float* __restrict__ Wd,
                              const float* __restrict__ bd, float* __restrict__ out) {
    int tid = threadIdx.x;
    int pos = blockIdx.x * 4 + (tid >> 6);
    int lane = tid & 63;
    float acc = 0.f;
#pragma unroll
    for (int q = 0; q < 4; q++) {
        int c = lane + q * 64;
        acc += __bfloat162float(H[(size_t)pos * CDIM + c]) * Wd[c];
    }
#pragma unroll
    for (int off = 32; off > 0; off >>= 1) acc += __shfl_down(acc, off);
    if (lane == 0) out[pos] = 1.f / (1.f + expf(-(acc + bd[0])));
}

extern "C" void kernel_launch(void* const* d_in, const int* in_sizes, int n_in,
                              void* d_out, int out_size, void* d_ws, size_t ws_size,
                              hipStream_t stream) {
    const float* x     = (const float*)d_in[0];
    const float* noise = (const float*)d_in[1];
    const float* rnd   = (const float*)d_in[2];
    const float* We    = (const float*)d_in[3];
    const float* pe    = (const float*)d_in[4];
    const float* Wq    = (const float*)d_in[5];
    const float* Wkv   = (const float*)d_in[6];
    const float* Wo    = (const float*)d_in[7];
    const float* bo    = (const float*)d_in[8];
    const float* Wd    = (const float*)d_in[9];
    const float* bd    = (const float*)d_in[10];
    float* out = (float*)d_out;

    // ws: H | Hn | WqkvT[2][2304][256] | WoT[2][256][768] | bsum f32[512] | QKV chunk | O chunk
    bf16* H     = (bf16*)d_ws;
    bf16* Hn    = H + (size_t)NPOS * CDIM;
    bf16* WqkvT = Hn + (size_t)NPOS * CDIM;
    bf16* WoT   = WqkvT + (size_t)2 * 2304 * 256;
    float* bsum = (float*)(WoT + (size_t)2 * 256 * 768);
    bf16* QKV   = (bf16*)(bsum + 512);

    size_t fixed = ((size_t)2 * NPOS * CDIM + (size_t)2 * 2304 * 256 + (size_t)2 * 256 * 768) * 2
                   + 512 * 4;
    int c = 4;
    while (c < 64 && fixed + (size_t)(NPOS / c) * (2304 + 768) * 2 > ws_size) c <<= 1;
    int mc = NPOS / c;  // multiple of 160 and 128 for all c
    bf16* O = QKV + (size_t)mc * 2304;

    pack_qkv_kernel<<<6 * 768, 256, 0, stream>>>(Wq, Wkv, WqkvT);
    pack_wo_kernel<<<2 * 256, 256, 0, stream>>>(Wo, WoT);
    bias3_kernel<<<2, 256, 0, stream>>>(bo, bsum);
    encode_kernel<<<NPOS, 256, 0, stream>>>(x, noise, rnd, We, pe, H);

    int nMblk = mc / 128;
    int n0 = (mc / 160) * 20 / 4, n1 = (mc / 160) * 40 / 4, n2 = (mc / 160) * 32 / 4;
    for (int l = 0; l < 2; l++) {
        for (int ci = 0; ci < c; ci++) {
            // LRU alignment: layer 0 walks chunks high->low (encoder wrote low->high, tail is
            // L3-hot); layer 1 walks low->high (layer 0 then wrote high->low... its tail = 0).
            int ch = (l == 0) ? (c - 1 - ci) : ci;
            const bf16* Hc = H + (size_t)ch * mc * CDIM;
            bf16* Hnc      = Hn + (size_t)ch * mc * CDIM;
            // QKV for ALL 3 axes in one GEMM: N = 2304, B in registers
            gemm_breg<<<nMblk * 18, 256, 0, stream>>>(
                Hc, CDIM, WqkvT + (size_t)l * 2304 * 256, QKV, 2304, 18);
            // all 3 axial attentions, one dispatch
            attn_all<<<n0 + n1 + n2, 256, 0, stream>>>(QKV, O, n0, n1);
            // Wo for all 3 axes as one K=768 GEMM; bias + leaky fused; no RMW
            gemm_bt<<<nMblk * 2, 256, 0, stream>>>(
                O, 768, WoT + (size_t)l * 256 * 768, 768, Hnc, CDIM, 2, 1, bsum + l * CDIM);
        }
        bf16* tmp = H; H = Hn; Hn = tmp;
    }

    decode_kernel<<<NPOS / 4, 256, 0, stream>>>(H, Wd, bd, out);
}

// Round 9
// 839.501 us; speedup vs baseline: 1.2716x; 1.2716x over previous
//
#include <hip/hip_runtime.h>
#include <hip/hip_bf16.h>
#include <math.h>

#define NPOS 81920   // 512*8*4*5
#define CDIM 256
#define SIGMA 1e-4f
#define LEAK 0.2f

typedef __hip_bfloat16 bf16;
typedef __bf16 bf16x8 __attribute__((ext_vector_type(8)));
typedef float f32x4 __attribute__((ext_vector_type(4)));

__device__ __forceinline__ float bf2f(unsigned short u) {
    return __uint_as_float(((unsigned)u) << 16);
}
__device__ __forceinline__ unsigned short f2bfu(float f) {
    bf16 h = __float2bfloat16(f);
    return *reinterpret_cast<unsigned short*>(&h);
}

// ---------------- encoder: h = tanh([x+sigma*noise, rand] @ W_enc) + pos_emb ----------------
__global__ void encode_kernel(const float* __restrict__ x, const float* __restrict__ noise,
                              const float* __restrict__ rnd, const float* __restrict__ We,
                              const float* __restrict__ pe, bf16* __restrict__ H) {
    int p = blockIdx.x;
    int c = threadIdx.x;
    float a = x[p] + SIGMA * noise[p];
    float b = rnd[p];
    float v = tanhf(a * We[c] + b * We[CDIM + c]) + pe[(p % 160) * CDIM + c];
    H[(size_t)p * CDIM + c] = __float2bfloat16(v);
}

// ---------------- bsum[l][c] = bo[l,0,c]+bo[l,1,c]+bo[l,2,c] ----------------
__global__ void bias3_kernel(const float* __restrict__ bo, float* __restrict__ bsum) {
    int l = blockIdx.x, c = threadIdx.x;
    bsum[l * CDIM + c] = bo[l * 768 + c] + bo[l * 768 + 256 + c] + bo[l * 768 + 512 + c];
}

// ---------------- weight packs ----------------
// WqkvT layout [l][a*768+n][k] (== [l][2304][256] B^T): n<256 -> Wq, else Wkv (k then v)
__global__ void pack_qkv_kernel(const float* __restrict__ Wq, const float* __restrict__ Wkv,
                                bf16* __restrict__ out) {
    int mat = blockIdx.x / 768;
    int n = blockIdx.x % 768;
    int k = threadIdx.x;
    float v = (n < 256) ? Wq[(size_t)mat * 65536 + (size_t)k * 256 + n]
                        : Wkv[(size_t)mat * 131072 + (size_t)k * 512 + (n - 256)];
    out[(size_t)blockIdx.x * 256 + k] = __float2bfloat16(v);
}
// WoT layout [l][n][a*256+ck] (== [l][256][768] B^T over stacked K): = Wo[l][a][ck][n]
__global__ void pack_wo_kernel(const float* __restrict__ Wo, bf16* __restrict__ out) {
    int l = blockIdx.x / 256;
    int n = blockIdx.x % 256;
    int ck = threadIdx.x;
    for (int a = 0; a < 3; a++)
        out[(size_t)(l * 256 + n) * 768 + a * 256 + ck] =
            __float2bfloat16(Wo[(((size_t)(l * 3 + a)) * 256 + ck) * 256 + n]);
}

// ---------------- pipelined bf16 MFMA GEMM: C[M x N] = A[M x K] @ B^T[N x K]^T --------------
// 128x128 tile, BK=64, DOUBLE-BUFFERED LDS with stage-after-barrier: the barrier drains the
// stage issued before it while the next tile's global_load_lds flies during compute.
// K is a template param so the loop fully unrolls and buffer indices are compile-time.
// XOR-swizzled LDS (chunk ^= row&7): measured 0 bank conflicts (round 7).
// mode: 0 = store; 1 = store + bias[col] + leaky-relu.
template <int K>
__global__ __launch_bounds__(256) void gemm_pipe(const bf16* __restrict__ A, int lda,
                                                 const bf16* __restrict__ Bt,
                                                 bf16* __restrict__ C, int ldc,
                                                 int nNblk, int mode,
                                                 const float* __restrict__ bias) {
    __shared__ __bf16 Asb[2][128 * 64];
    __shared__ __bf16 Bsb[2][128 * 64];
    int tid = threadIdx.x;
    int wave = tid >> 6, lane = tid & 63;
    int quad = lane >> 4, m = lane & 15;
    int nMblk = gridDim.x / nNblk;
    int mb, nb;
    if ((nMblk & 7) == 0) {
        int xcd = blockIdx.x & 7, slot = blockIdx.x >> 3;
        int g = slot / nNblk;
        nb = slot - g * nNblk;
        mb = xcd + 8 * g;
    } else {
        mb = blockIdx.x / nNblk;
        nb = blockIdx.x - mb * nNblk;
    }
    int bm = mb * 128, bn = nb * 128;
    int wr = (wave >> 1) * 64, wc = (wave & 1) * 64;
    f32x4 acc[4][4] = {};

#define STAGE(buf, k0)                                                                         \
    {                                                                                          \
        _Pragma("unroll") for (int rep = 0; rep < 4; rep++) {                                  \
            int ch = rep * 256 + wave * 64 + lane;                                             \
            int row = ch >> 3, cc = ch & 7, gc = cc ^ (row & 7);                               \
            __builtin_amdgcn_global_load_lds(                                                  \
                (const __attribute__((address_space(1))) void*)(A + (size_t)(bm + row) * lda   \
                                                                + (k0) + gc * 8),              \
                (__attribute__((address_space(3))) void*)(&Asb[buf][(rep * 256 + wave * 64) * 8]), \
                16, 0, 0);                                                                     \
        }                                                                                      \
        _Pragma("unroll") for (int rep = 0; rep < 4; rep++) {                                  \
            int ch = rep * 256 + wave * 64 + lane;                                             \
            int row = ch >> 3, cc = ch & 7, gc = cc ^ (row & 7);                               \
            __builtin_amdgcn_global_load_lds(                                                  \
                (const __attribute__((address_space(1))) void*)(Bt + (size_t)(bn + row) * K    \
                                                                + (k0) + gc * 8),              \
                (__attribute__((address_space(3))) void*)(&Bsb[buf][(rep * 256 + wave * 64) * 8]), \
                16, 0, 0);                                                                     \
        }                                                                                      \
    }

    constexpr int NIT = K / 64;
    STAGE(0, 0);
#pragma unroll
    for (int it = 0; it < NIT; it++) {
        __syncthreads();                       // drains STAGE(it); joins readers of buf it^1
        if (it + 1 < NIT) STAGE((it + 1) & 1, (it + 1) * 64);  // overlaps compute below
        const __bf16* Ab = Asb[it & 1];
        const __bf16* Bb = Bsb[it & 1];
#pragma unroll
        for (int kk = 0; kk < 2; kk++) {
            bf16x8 af[4], bfr[4];
#pragma unroll
            for (int i = 0; i < 4; i++) {
                int r = wr + i * 16 + m, cix = kk * 4 + quad;
                af[i] = *(const bf16x8*)(Ab + r * 64 + ((cix ^ (r & 7)) * 8));
            }
#pragma unroll
            for (int j = 0; j < 4; j++) {
                int r = wc + j * 16 + m, cix = kk * 4 + quad;
                bfr[j] = *(const bf16x8*)(Bb + r * 64 + ((cix ^ (r & 7)) * 8));
            }
#pragma unroll
            for (int i = 0; i < 4; i++)
#pragma unroll
                for (int j = 0; j < 4; j++)
                    acc[i][j] = __builtin_amdgcn_mfma_f32_16x16x32_bf16(af[i], bfr[j], acc[i][j], 0, 0, 0);
        }
    }
#undef STAGE

    // epilogue: C/D layout col = lane&15, row = quad*4 + r
#pragma unroll
    for (int i = 0; i < 4; i++) {
#pragma unroll
        for (int j = 0; j < 4; j++) {
#pragma unroll
            for (int r = 0; r < 4; r++) {
                int row = bm + wr + i * 16 + quad * 4 + r;
                int col = bn + wc + j * 16 + m;
                float v = acc[i][j][r];
                if (mode == 1) {
                    v += bias[col];
                    v = v >= 0.f ? v : LEAK * v;
                }
                C[(size_t)row * ldc + col] = __float2bfloat16(v);
            }
        }
    }
}

// ---------------- fused axial attention: all 3 axes, one dispatch ----------------
// QKV row = 2304 bf16 (= 3 x [q|k|v]); output -> O row = 768 bf16 (= [o0|o1|o2]).
template <int AXIS>
__device__ __forceinline__ void attn_axis(const bf16* __restrict__ QKV, bf16* __restrict__ O,
                                          int seq, int lane) {
    constexpr int T      = (AXIS == 0) ? 8 : (AXIS == 1) ? 4 : 5;
    constexpr int STRIDE = (AXIS == 0) ? 20 : (AXIS == 1) ? 5 : 1;
    int base;
    if (AXIS == 0)      { int b = seq / 20, r = seq % 20; base = b * 160 + r; }
    else if (AXIS == 1) { int b = seq / 40, r = seq % 40; base = b * 160 + (r / 5) * 20 + (r % 5); }
    else                { int b = seq / 32, r = seq % 32; base = b * 160 + r * 5; }

    float q[T][4], k[T][4], v[T][4];
#pragma unroll
    for (int t = 0; t < T; t++) {
        const unsigned short* rowp =
            (const unsigned short*)QKV + (size_t)(base + t * STRIDE) * 2304 + AXIS * 768 + lane * 4;
        ushort4 qu = *(const ushort4*)(rowp);
        ushort4 ku = *(const ushort4*)(rowp + 256);
        ushort4 vu = *(const ushort4*)(rowp + 512);
        q[t][0] = bf2f(qu.x); q[t][1] = bf2f(qu.y); q[t][2] = bf2f(qu.z); q[t][3] = bf2f(qu.w);
        k[t][0] = bf2f(ku.x); k[t][1] = bf2f(ku.y); k[t][2] = bf2f(ku.z); k[t][3] = bf2f(ku.w);
        v[t][0] = bf2f(vu.x); v[t][1] = bf2f(vu.y); v[t][2] = bf2f(vu.z); v[t][3] = bf2f(vu.w);
    }

#pragma unroll
    for (int t = 0; t < T; t++) {
        float sc[T];
#pragma unroll
        for (int s = 0; s < T; s++) {
            float p = q[t][0] * k[s][0] + q[t][1] * k[s][1] + q[t][2] * k[s][2] + q[t][3] * k[s][3];
            p += __shfl_xor(p, 1);
            p += __shfl_xor(p, 2);
            sc[s] = p * 0.25f;  // * DH^-0.5
        }
        float mx = sc[0];
#pragma unroll
        for (int s = 1; s < T; s++) mx = fmaxf(mx, sc[s]);
        float sum = 0.f;
#pragma unroll
        for (int s = 0; s < T; s++) { sc[s] = __expf(sc[s] - mx); sum += sc[s]; }
        float inv = 1.f / sum;
        float o0 = 0.f, o1 = 0.f, o2 = 0.f, o3 = 0.f;
#pragma unroll
        for (int s = 0; s < T; s++) {
            o0 += sc[s] * v[s][0]; o1 += sc[s] * v[s][1];
            o2 += sc[s] * v[s][2]; o3 += sc[s] * v[s][3];
        }
        ushort4 st;
        st.x = f2bfu(o0 * inv); st.y = f2bfu(o1 * inv);
        st.z = f2bfu(o2 * inv); st.w = f2bfu(o3 * inv);
        *(ushort4*)((unsigned short*)O + (size_t)(base + t * STRIDE) * 768 + AXIS * 256 + lane * 4) = st;
    }
}

__global__ __launch_bounds__(256) void attn_all(const bf16* __restrict__ QKV,
                                                bf16* __restrict__ O, int n0, int n1) {
    int wave = threadIdx.x >> 6, lane = threadIdx.x & 63;
    int blk = blockIdx.x;
    if (blk < n0)            attn_axis<0>(QKV, O, blk * 4 + wave, lane);
    else if (blk < n0 + n1)  attn_axis<1>(QKV, O, (blk - n0) * 4 + wave, lane);
    else                     attn_axis<2>(QKV, O, (blk - n0 - n1) * 4 + wave, lane);
}

// ---------------- decoder: out = sigmoid(H @ Wd + bd) ----------------
__global__ void decode_kernel(const bf16* __restrict__ H, const float* __restrict__ Wd,
                              const float* __restrict__ bd, float* __restrict__ out) {
    int tid = threadIdx.x;
    int pos = blockIdx.x * 4 + (tid >> 6);
    int lane = tid & 63;
    float acc = 0.f;
#pragma unroll
    for (int q = 0; q < 4; q++) {
        int c = lane + q * 64;
        acc += __bfloat162float(H[(size_t)pos * CDIM + c]) * Wd[c];
    }
#pragma unroll
    for (int off = 32; off > 0; off >>= 1) acc += __shfl_down(acc, off);
    if (lane == 0) out[pos] = 1.f / (1.f + expf(-(acc + bd[0])));
}

extern "C" void kernel_launch(void* const* d_in, const int* in_sizes, int n_in,
                              void* d_out, int out_size, void* d_ws, size_t ws_size,
                              hipStream_t stream) {
    const float* x     = (const float*)d_in[0];
    const float* noise = (const float*)d_in[1];
    const float* rnd   = (const float*)d_in[2];
    const float* We    = (const float*)d_in[3];
    const float* pe    = (const float*)d_in[4];
    const float* Wq    = (const float*)d_in[5];
    const float* Wkv   = (const float*)d_in[6];
    const float* Wo    = (const float*)d_in[7];
    const float* bo    = (const float*)d_in[8];
    const float* Wd    = (const float*)d_in[9];
    const float* bd    = (const float*)d_in[10];
    float* out = (float*)d_out;

    // ws: H | Hn | WqkvT[2][2304][256] | WoT[2][256][768] | bsum f32[512] | QKV chunk | O chunk
    bf16* H     = (bf16*)d_ws;
    bf16* Hn    = H + (size_t)NPOS * CDIM;
    bf16* WqkvT = Hn + (size_t)NPOS * CDIM;
    bf16* WoT   = WqkvT + (size_t)2 * 2304 * 256;
    float* bsum = (float*)(WoT + (size_t)2 * 256 * 768);
    bf16* QKV   = (bf16*)(bsum + 512);

    size_t fixed = ((size_t)2 * NPOS * CDIM + (size_t)2 * 2304 * 256 + (size_t)2 * 256 * 768) * 2
                   + 512 * 4;
    int c = 4;
    while (c < 64 && fixed + (size_t)(NPOS / c) * (2304 + 768) * 2 > ws_size) c <<= 1;
    int mc = NPOS / c;  // multiple of 160 and 128 for all c
    bf16* O = QKV + (size_t)mc * 2304;

    pack_qkv_kernel<<<6 * 768, 256, 0, stream>>>(Wq, Wkv, WqkvT);
    pack_wo_kernel<<<2 * 256, 256, 0, stream>>>(Wo, WoT);
    bias3_kernel<<<2, 256, 0, stream>>>(bo, bsum);
    encode_kernel<<<NPOS, 256, 0, stream>>>(x, noise, rnd, We, pe, H);

    int nMblk = mc / 128;
    int n0 = (mc / 160) * 20 / 4, n1 = (mc / 160) * 40 / 4, n2 = (mc / 160) * 32 / 4;
    for (int l = 0; l < 2; l++) {
        for (int ch = 0; ch < c; ch++) {
            const bf16* Hc = H + (size_t)ch * mc * CDIM;
            bf16* Hnc      = Hn + (size_t)ch * mc * CDIM;
            // QKV for ALL 3 axes in one GEMM: N = 2304, pipelined K-loop
            gemm_pipe<256><<<nMblk * 18, 256, 0, stream>>>(
                Hc, CDIM, WqkvT + (size_t)l * 2304 * 256, QKV, 2304, 18, 0, nullptr);
            // all 3 axial attentions, one dispatch
            attn_all<<<n0 + n1 + n2, 256, 0, stream>>>(QKV, O, n0, n1);
            // Wo for all 3 axes as one K=768 GEMM; bias + leaky fused; no RMW
            gemm_pipe<768><<<nMblk * 2, 256, 0, stream>>>(
                O, 768, WoT + (size_t)l * 256 * 768, Hnc, CDIM, 2, 1, bsum + l * CDIM);
        }
        bf16* tmp = H; H = Hn; Hn = tmp;
    }

    decode_kernel<<<NPOS / 4, 256, 0, stream>>>(H, Wd, bd, out);
}